// Round 1
// baseline (660.979 us; speedup 1.0000x reference)
//
#include <hip/hip_runtime.h>
#include <math.h>

static constexpr int B_ = 4;
static constexpr int C_ = 256;
static constexpr int PD_ = 64;
static constexpr int N_ = 4096;
static constexpr int O96_ = 96;
static constexpr float EPS_ = 1e-5f;
static constexpr float SCALE_ = 0.25f;   // 16^-0.5

// ---------------- GroupNorm: per-(b,c) partial sums ----------------
__global__ __launch_bounds__(256) void k_gn_part(const float* __restrict__ x,
                                                 float* __restrict__ part) {
    const int blk = blockIdx.x;            // b*64 + c
    const int b = blk >> 6, c = blk & 63;
    const float* p = x + (size_t)(b * C_ + c) * N_;
    float s = 0.f, q = 0.f;
    for (int i = threadIdx.x; i < N_; i += 256) {
        float v = p[i]; s += v; q += v * v;
    }
    for (int d = 1; d < 64; d <<= 1) {
        s += __shfl_xor(s, d, 64);
        q += __shfl_xor(q, d, 64);
    }
    __shared__ float ls[4], lq[4];
    const int lane = threadIdx.x & 63, wid = threadIdx.x >> 6;
    if (lane == 0) { ls[wid] = s; lq[wid] = q; }
    __syncthreads();
    if (threadIdx.x == 0) {
        part[2 * blk]     = ls[0] + ls[1] + ls[2] + ls[3];
        part[2 * blk + 1] = lq[0] + lq[1] + lq[2] + lq[3];
    }
}

// ---------------- GroupNorm: finalize mean/rstd per batch ----------------
__global__ __launch_bounds__(64) void k_gn_fin(const float* __restrict__ part,
                                               float* __restrict__ stats) {
    const int b = blockIdx.x;
    float s = part[2 * (b * 64 + threadIdx.x)];
    float q = part[2 * (b * 64 + threadIdx.x) + 1];
    for (int d = 1; d < 64; d <<= 1) {
        s += __shfl_xor(s, d, 64);
        q += __shfl_xor(q, d, 64);
    }
    if (threadIdx.x == 0) {
        const float inv_n = 1.0f / (float)(PD_ * N_);
        float mu = s * inv_n;
        float var = q * inv_n - mu * mu;
        stats[2 * b]     = mu;
        stats[2 * b + 1] = rsqrtf(var + EPS_);
    }
}

// ---------------- fused GN-apply + QKV 1x1 conv + BN (scale folded into q) ----------------
__global__ __launch_bounds__(256) void k_qkv(const float* __restrict__ x,
        const float* __restrict__ gnw, const float* __restrict__ gnb,
        const float* __restrict__ qw,  const float* __restrict__ bnw,
        const float* __restrict__ bnb, const float* __restrict__ rm,
        const float* __restrict__ rv,  const float* __restrict__ stats,
        float* __restrict__ qkv) {
    __shared__ float wl[O96_ * PD_];
    __shared__ float binv[O96_], bbeta[O96_];
    const int t = threadIdx.x;
    const int b = blockIdx.x >> 6;
    const int n0 = (blockIdx.x & 63) << 6;
    for (int i = t; i < O96_ * PD_; i += 256) wl[i] = qw[i];
    for (int o = t; o < O96_; o += 256) {
        float inv  = bnw[o] * rsqrtf(rv[o] + EPS_);
        float beta = bnb[o] - rm[o] * inv;
        if (o < 16) { inv *= SCALE_; beta *= SCALE_; }
        binv[o] = inv; bbeta[o] = beta;
    }
    const float mu = stats[2 * b], rs = stats[2 * b + 1];
    __syncthreads();
    const int n  = n0 + (t & 63);
    const int og = t >> 6;                  // 0..3, splits the 96 outputs
    float xn[PD_];
    const float* xb = x + (size_t)b * C_ * N_ + n;
    #pragma unroll
    for (int c = 0; c < PD_; ++c)
        xn[c] = (xb[(size_t)c * N_] - mu) * rs * gnw[c] + gnb[c];
    float* qb = qkv + (size_t)b * O96_ * N_ + n;
    for (int o = og * 24; o < og * 24 + 24; ++o) {
        const float4* wr = (const float4*)&wl[o * PD_];
        float a = 0.f;
        #pragma unroll
        for (int c4 = 0; c4 < 16; ++c4) {
            float4 w4 = wr[c4];
            a += w4.x * xn[4*c4] + w4.y * xn[4*c4+1] + w4.z * xn[4*c4+2] + w4.w * xn[4*c4+3];
        }
        qb[(size_t)o * N_] = a * binv[o] + bbeta[o];
    }
}

// ---------------- flash attention: 64-query tile per block ----------------
__global__ __launch_bounds__(256) void k_attn(const float* __restrict__ qkv,
                                              float* __restrict__ x1o) {
    __shared__ float ks[16 * 64];          // [c][mm]
    __shared__ float vs[64 * 64];          // [p][mm]  (reads are wave-broadcast)
    __shared__ float ps[64 * 68];          // [qi][mm] pitch 68 (=17 float4, odd)
    __shared__ float rowF[64], rowS[64];
    const int t  = threadIdx.x;
    const int b  = blockIdx.x >> 6;
    const int n0 = (blockIdx.x & 63) << 6;
    const float* qkb = qkv + (size_t)b * O96_ * N_;

    const int qiA = t >> 2, j = t & 3;     // score mapping: 4 lanes per query row
    const int qiB = t & 63, pg = t >> 6;   // PV mapping: lane=query col, wave=16 p's

    float qreg[16];
    #pragma unroll
    for (int c = 0; c < 16; ++c)
        qreg[c] = qkb[(size_t)c * N_ + n0 + qiA];   // q already has SCALE folded

    float M = -INFINITY, S = 0.f;
    float acc[16];
    #pragma unroll
    for (int k = 0; k < 16; ++k) acc[k] = 0.f;

    for (int mc = 0; mc < 64; ++mc) {
        const int m0 = mc << 6;
        __syncthreads();                   // prev PV done before restaging
        #pragma unroll
        for (int i = 0; i < 4; ++i) {      // stage K chunk 16x64
            int idx = t + i * 256;
            int c = idx >> 6, mm = idx & 63;
            ks[idx] = qkb[(size_t)(16 + c) * N_ + m0 + mm];
        }
        #pragma unroll
        for (int i = 0; i < 16; ++i) {     // stage V chunk 64x64
            int idx = t + i * 256;
            int p = idx >> 6, mm = idx & 63;
            vs[idx] = qkb[(size_t)(32 + p) * N_ + m0 + mm];
        }
        __syncthreads();

        // ---- scores: this thread's 16 m's (m = j*16 + i) for query qiA ----
        float s[16];
        #pragma unroll
        for (int i = 0; i < 16; ++i) s[i] = 0.f;
        #pragma unroll
        for (int c = 0; c < 16; ++c) {
            const float qc = qreg[c];
            const float4* kr = (const float4*)&ks[c * 64 + j * 16];
            float4 k0 = kr[0], k1 = kr[1], k2 = kr[2], k3 = kr[3];
            s[0]  += qc*k0.x; s[1]  += qc*k0.y; s[2]  += qc*k0.z; s[3]  += qc*k0.w;
            s[4]  += qc*k1.x; s[5]  += qc*k1.y; s[6]  += qc*k1.z; s[7]  += qc*k1.w;
            s[8]  += qc*k2.x; s[9]  += qc*k2.y; s[10] += qc*k2.z; s[11] += qc*k2.w;
            s[12] += qc*k3.x; s[13] += qc*k3.y; s[14] += qc*k3.z; s[15] += qc*k3.w;
        }
        float mx = s[0];
        #pragma unroll
        for (int i = 1; i < 16; ++i) mx = fmaxf(mx, s[i]);
        mx = fmaxf(mx, __shfl_xor(mx, 1, 64));
        mx = fmaxf(mx, __shfl_xor(mx, 2, 64));
        const float Mnew = fmaxf(M, mx);
        const float f = __expf(M - Mnew);
        float psum = 0.f;
        #pragma unroll
        for (int i = 0; i < 16; ++i) { s[i] = __expf(s[i] - Mnew); psum += s[i]; }
        psum += __shfl_xor(psum, 1, 64);
        psum += __shfl_xor(psum, 2, 64);
        S = S * f + psum;
        M = Mnew;
        float4* pwr = (float4*)&ps[qiA * 68 + j * 16];
        pwr[0] = make_float4(s[0],  s[1],  s[2],  s[3]);
        pwr[1] = make_float4(s[4],  s[5],  s[6],  s[7]);
        pwr[2] = make_float4(s[8],  s[9],  s[10], s[11]);
        pwr[3] = make_float4(s[12], s[13], s[14], s[15]);
        if (j == 0) rowF[qiA] = f;
        __syncthreads();

        // ---- PV: out[p, qiB] += sum_m V[p,m] * P[qiB,m] ----
        const float f2 = rowF[qiB];
        #pragma unroll
        for (int k = 0; k < 16; ++k) acc[k] *= f2;
        const float4* pr = (const float4*)&ps[qiB * 68];
        #pragma unroll
        for (int m4 = 0; m4 < 16; ++m4) {
            float4 pv = pr[m4];
            #pragma unroll
            for (int k = 0; k < 16; ++k) {
                float4 vv = ((const float4*)&vs[(pg * 16 + k) * 64])[m4];
                acc[k] += pv.x*vv.x + pv.y*vv.y + pv.z*vv.z + pv.w*vv.w;
            }
        }
    }
    if (j == 0) rowS[qiA] = S;
    __syncthreads();
    const float is = 1.0f / rowS[qiB];
    float* ob = x1o + (size_t)b * PD_ * N_ + n0 + qiB;
    #pragma unroll
    for (int k = 0; k < 16; ++k)
        ob[(size_t)(pg * 16 + k) * N_] = acc[k] * is;
}

// ---------------- SiLU + proj 1x1 conv + BN ----------------
__global__ __launch_bounds__(256) void k_proj(const float* __restrict__ x,
        const float* __restrict__ x1o, const float* __restrict__ pw,
        const float* __restrict__ bnw, const float* __restrict__ bnb,
        const float* __restrict__ rm,  const float* __restrict__ rv,
        float* __restrict__ out) {
    __shared__ float ys[64 * 68];          // [nn][cc] pitch 68
    __shared__ float wl[64 * 68];          // [oo][cc] pitch 68
    const int t  = threadIdx.x;
    const int nt = blockIdx.x & 255;
    const int o0 = (blockIdx.x >> 8) << 6;
    const int b  = nt >> 6;
    const int n0 = (nt & 63) << 6;
    const int nn = t & 63, og = t >> 6;
    float acc[16];
    #pragma unroll
    for (int k = 0; k < 16; ++k) acc[k] = 0.f;

    for (int c0 = 0; c0 < C_; c0 += 64) {
        __syncthreads();
        #pragma unroll
        for (int i = 0; i < 16; ++i) {     // stage silu(y) tile 64c x 64n -> [nn][cc]
            int idx = t + i * 256;
            int cc = idx >> 6, ln = idx & 63;
            int cg = c0 + cc;
            float v;
            if (cg < PD_) v = x1o[(size_t)b * PD_ * N_ + (size_t)cg * N_ + n0 + ln];
            else          v = x[(size_t)(b * C_ + cg) * N_ + n0 + ln];
            v = v / (1.0f + __expf(-v));
            ys[ln * 68 + cc] = v;
        }
        #pragma unroll
        for (int i = 0; i < 16; ++i) {     // stage w tile 64o x 64c
            int idx = t + i * 256;
            int oo = idx >> 6, cc = idx & 63;
            wl[oo * 68 + cc] = pw[(size_t)(o0 + oo) * C_ + c0 + cc];
        }
        __syncthreads();
        const float4* yr = (const float4*)&ys[nn * 68];
        #pragma unroll
        for (int c4 = 0; c4 < 16; ++c4) {
            float4 yv = yr[c4];
            #pragma unroll
            for (int k = 0; k < 16; ++k) {
                float4 wv = ((const float4*)&wl[(og * 16 + k) * 68])[c4];
                acc[k] += yv.x*wv.x + yv.y*wv.y + yv.z*wv.z + yv.w*wv.w;
            }
        }
    }
    #pragma unroll
    for (int k = 0; k < 16; ++k) {
        const int o = o0 + og * 16 + k;
        float inv  = bnw[o] * rsqrtf(rv[o] + EPS_);
        float beta = bnb[o] - rm[o] * inv;
        out[(size_t)(b * C_ + o) * N_ + n0 + nn] = acc[k] * inv + beta;
    }
}

extern "C" void kernel_launch(void* const* d_in, const int* in_sizes, int n_in,
                              void* d_out, int out_size, void* d_ws, size_t ws_size,
                              hipStream_t stream) {
    const float* x   = (const float*)d_in[0];
    const float* gnw = (const float*)d_in[1];
    const float* gnb = (const float*)d_in[2];
    const float* qw  = (const float*)d_in[3];
    const float* qbw = (const float*)d_in[4];
    const float* qbb = (const float*)d_in[5];
    const float* qrm = (const float*)d_in[6];
    const float* qrv = (const float*)d_in[7];
    const float* pw  = (const float*)d_in[8];
    const float* pbw = (const float*)d_in[9];
    const float* pbb = (const float*)d_in[10];
    const float* prm = (const float*)d_in[11];
    const float* prv = (const float*)d_in[12];
    float* out = (float*)d_out;
    float* ws  = (float*)d_ws;

    float* part  = ws;                                    // 512 floats
    float* stats = ws + 512;                              // 8 floats
    float* qkv   = ws + 1024;                             // 4*96*4096
    float* x1o   = ws + 1024 + (size_t)B_ * O96_ * N_;    // 4*64*4096

    k_gn_part<<<256, 256, 0, stream>>>(x, part);
    k_gn_fin<<<4, 64, 0, stream>>>(part, stats);
    k_qkv<<<256, 256, 0, stream>>>(x, gnw, gnb, qw, qbw, qbb, qrm, qrv, stats, qkv);
    k_attn<<<256, 256, 0, stream>>>(qkv, x1o);
    k_proj<<<1024, 256, 0, stream>>>(x, x1o, pw, pbw, pbb, prm, prv, out);
}

// Round 3
// 246.188 us; speedup vs baseline: 2.6849x; 2.6849x over previous
//
#include <hip/hip_runtime.h>
#include <math.h>

static constexpr int B_ = 4;
static constexpr int C_ = 256;
static constexpr int PD_ = 64;
static constexpr int N_ = 4096;
static constexpr int O96_ = 96;
static constexpr float EPS_ = 1e-5f;
static constexpr float SCALE_ = 0.25f;   // 16^-0.5

typedef __attribute__((ext_vector_type(8))) short short8v;
typedef __attribute__((ext_vector_type(4))) float f32x4;

__device__ inline short f2bf(float x) {
    union { float f; unsigned u; } v; v.f = x;
    unsigned r = v.u + 0x7FFF + ((v.u >> 16) & 1);   // RNE
    return (short)(r >> 16);
}

// ---------------- GroupNorm: per-(b,c) partial sums ----------------
__global__ __launch_bounds__(256) void k_gn_part(const float* __restrict__ x,
                                                 float* __restrict__ part) {
    const int blk = blockIdx.x;            // b*64 + c
    const int b = blk >> 6, c = blk & 63;
    const float* p = x + (size_t)(b * C_ + c) * N_;
    float s = 0.f, q = 0.f;
    for (int i = threadIdx.x; i < N_; i += 256) {
        float v = p[i]; s += v; q += v * v;
    }
    for (int d = 1; d < 64; d <<= 1) {
        s += __shfl_xor(s, d, 64);
        q += __shfl_xor(q, d, 64);
    }
    __shared__ float ls[4], lq[4];
    const int lane = threadIdx.x & 63, wid = threadIdx.x >> 6;
    if (lane == 0) { ls[wid] = s; lq[wid] = q; }
    __syncthreads();
    if (threadIdx.x == 0) {
        part[2 * blk]     = ls[0] + ls[1] + ls[2] + ls[3];
        part[2 * blk + 1] = lq[0] + lq[1] + lq[2] + lq[3];
    }
}

// ---------------- GroupNorm: finalize mean/rstd per batch ----------------
__global__ __launch_bounds__(64) void k_gn_fin(const float* __restrict__ part,
                                               float* __restrict__ stats) {
    const int b = blockIdx.x;
    float s = part[2 * (b * 64 + threadIdx.x)];
    float q = part[2 * (b * 64 + threadIdx.x) + 1];
    for (int d = 1; d < 64; d <<= 1) {
        s += __shfl_xor(s, d, 64);
        q += __shfl_xor(q, d, 64);
    }
    if (threadIdx.x == 0) {
        const float inv_n = 1.0f / (float)(PD_ * N_);
        float mu = s * inv_n;
        float var = q * inv_n - mu * mu;
        stats[2 * b]     = mu;
        stats[2 * b + 1] = rsqrtf(var + EPS_);
    }
}

// ------- fused GN-apply + QKV 1x1 conv + BN -> bf16 (scale folded into q) -------
__global__ __launch_bounds__(256) void k_qkv(const float* __restrict__ x,
        const float* __restrict__ gnw, const float* __restrict__ gnb,
        const float* __restrict__ qw,  const float* __restrict__ bnw,
        const float* __restrict__ bnb, const float* __restrict__ rm,
        const float* __restrict__ rv,  const float* __restrict__ stats,
        short* __restrict__ qkvb) {
    __shared__ float wl[O96_ * PD_];
    __shared__ float binv[O96_], bbeta[O96_];
    const int t = threadIdx.x;
    const int b = blockIdx.x >> 6;
    const int n0 = (blockIdx.x & 63) << 6;
    for (int i = t; i < O96_ * PD_; i += 256) wl[i] = qw[i];
    for (int o = t; o < O96_; o += 256) {
        float inv  = bnw[o] * rsqrtf(rv[o] + EPS_);
        float beta = bnb[o] - rm[o] * inv;
        if (o < 16) { inv *= SCALE_; beta *= SCALE_; }
        binv[o] = inv; bbeta[o] = beta;
    }
    const float mu = stats[2 * b], rs = stats[2 * b + 1];
    __syncthreads();
    const int n  = n0 + (t & 63);
    const int og = t >> 6;                  // 0..3, splits the 96 outputs
    float xn[PD_];
    const float* xb = x + (size_t)b * C_ * N_ + n;
    #pragma unroll
    for (int c = 0; c < PD_; ++c)
        xn[c] = (xb[(size_t)c * N_] - mu) * rs * gnw[c] + gnb[c];
    short* qb = qkvb + (size_t)b * O96_ * N_ + n;
    for (int o = og * 24; o < og * 24 + 24; ++o) {
        const float4* wr = (const float4*)&wl[o * PD_];
        float a = 0.f;
        #pragma unroll
        for (int c4 = 0; c4 < 16; ++c4) {
            float4 w4 = wr[c4];
            a += w4.x * xn[4*c4] + w4.y * xn[4*c4+1] + w4.z * xn[4*c4+2] + w4.w * xn[4*c4+3];
        }
        qb[(size_t)o * N_] = f2bf(a * binv[o] + bbeta[o]);
    }
}

// ---------------- MFMA flash attention ----------------
// 64-q tile/block, 8 waves: waves 0-3 = even m-chunks, 4-7 = odd m-chunks.
// Wave handles 16 q rows.  Layout-permutation-safe fragments (A,B share k-map).
__global__ __launch_bounds__(512) void k_attn(const short* __restrict__ qkvb,
                                              float* __restrict__ x1o) {
    __shared__ __align__(16) char smem[46080];
    short* Qt     = (short*)smem;             // [64][24]
    short* KtBase = (short*)(smem + 3072);    // [2][64][24]
    short* VsBase = (short*)(smem + 9216);    // [2][64][72]
    short* PlBase = (short*)(smem + 27648);   // [8][16][72]
    float4* comb  = (float4*)(smem + 3072);   // overlay after loop: acc[16][64], ms[8][64]

    const int t    = threadIdx.x;
    const int b    = blockIdx.x >> 6;
    const int n0   = (blockIdx.x & 63) << 6;
    const int w    = t >> 6;
    const int lane = t & 63;
    const int qw   = w & 3;       // q sub-tile (16 rows)
    const int h    = w >> 2;      // m-parity group
    const int tg   = t & 255;
    const int g    = lane >> 4;   // 0..3
    const int col  = lane & 15;

    const short* qb = qkvb + (size_t)b * O96_ * N_;
    short* Kt = KtBase + h * 1536;
    short* Vs = VsBase + h * 4608;
    short* Pl = PlBase + w * 1152;

    // stage Q^T [q][c] once (bf16, scale pre-folded)
    #pragma unroll
    for (int i = 0; i < 2; ++i) {
        int idx = t + i * 512;
        int c = idx >> 6, q = idx & 63;
        Qt[q * 24 + c] = qb[(size_t)c * N_ + n0 + q];
    }

    f32x4 acc[4];
    #pragma unroll
    for (int pt = 0; pt < 4; ++pt) acc[pt] = 0.f;
    float Mr[4] = {-INFINITY, -INFINITY, -INFINITY, -INFINITY};
    float Sr[4] = {0.f, 0.f, 0.f, 0.f};
    short8v a_q = 0;

    for (int it = 0; it < 32; ++it) {
        const int m0 = (it * 2 + h) << 6;
        __syncthreads();
        // stage K chunk 16c x 64m -> Kt[m][c]
        #pragma unroll
        for (int i = 0; i < 4; ++i) {
            int idx = tg + i * 256;
            int c = idx >> 6, m = idx & 63;
            Kt[m * 24 + c] = qb[(size_t)(16 + c) * N_ + m0 + m];
        }
        // stage V chunk 64p x 64m -> Vs[p][m] (natural), short4
        #pragma unroll
        for (int i = 0; i < 4; ++i) {
            int idx = tg + i * 256;
            int p = idx >> 4, m4 = idx & 15;
            short4 v4 = *(const short4*)(qb + (size_t)(32 + p) * N_ + m0 + m4 * 4);
            *(short4*)(Vs + p * 72 + m4 * 4) = v4;
        }
        __syncthreads();
        if (it == 0) {
            if (g < 2) a_q = *(const short8v*)(Qt + (qw * 16 + col) * 24 + 8 * g);
        }
        // ---- QK^T: S[16q x 64m], K-dim c=16 zero-padded to 32 ----
        f32x4 s[4];
        #pragma unroll
        for (int mt = 0; mt < 4; ++mt) {
            short8v kb = 0;
            if (g < 2) kb = *(const short8v*)(Kt + (mt * 16 + col) * 24 + 8 * g);
            f32x4 z = 0.f;
            s[mt] = __builtin_amdgcn_mfma_f32_16x16x32_bf16(a_q, kb, z, 0, 0, 0);
        }
        // ---- online softmax (rows live in 16-lane groups) ----
        float f_[4];
        #pragma unroll
        for (int r = 0; r < 4; ++r) {
            float mx = fmaxf(fmaxf(s[0][r], s[1][r]), fmaxf(s[2][r], s[3][r]));
            mx = fmaxf(mx, __shfl_xor(mx, 1, 64));
            mx = fmaxf(mx, __shfl_xor(mx, 2, 64));
            mx = fmaxf(mx, __shfl_xor(mx, 4, 64));
            mx = fmaxf(mx, __shfl_xor(mx, 8, 64));
            float Mn = fmaxf(Mr[r], mx);
            f_[r] = __expf(Mr[r] - Mn);
            Mr[r] = Mn;
            float p0 = __expf(s[0][r] - Mn), p1 = __expf(s[1][r] - Mn);
            float p2 = __expf(s[2][r] - Mn), p3 = __expf(s[3][r] - Mn);
            s[0][r] = p0; s[1][r] = p1; s[2][r] = p2; s[3][r] = p3;
            float ps = p0 + p1 + p2 + p3;
            ps += __shfl_xor(ps, 1, 64);
            ps += __shfl_xor(ps, 2, 64);
            ps += __shfl_xor(ps, 4, 64);
            ps += __shfl_xor(ps, 8, 64);
            Sr[r] = Sr[r] * f_[r] + ps;
        }
        // ---- P -> bf16 -> wave-private LDS [16q][64m] pitch 72 ----
        #pragma unroll
        for (int mt = 0; mt < 4; ++mt)
            #pragma unroll
            for (int r = 0; r < 4; ++r)
                Pl[(g * 4 + r) * 72 + mt * 16 + col] = f2bf(s[mt][r]);
        // Cross-lane LDS handoff within the wave: LGKM ops may complete
        // out-of-order and the compiler sees no per-thread aliasing, so we
        // must drain the ds_writes before any lane's ds_read (guide rule #18).
        asm volatile("s_waitcnt lgkmcnt(0)" ::: "memory");
        __builtin_amdgcn_sched_barrier(0);
        // ---- rescale acc, then PV: O^T[16q x 64p] += P[16x64] * V^T[64x64p] ----
        #pragma unroll
        for (int pt = 0; pt < 4; ++pt)
            #pragma unroll
            for (int r = 0; r < 4; ++r)
                acc[pt][r] *= f_[r];
        #pragma unroll
        for (int ks = 0; ks < 2; ++ks) {
            short8v pa = *(const short8v*)(Pl + col * 72 + ks * 32 + 8 * g);
            #pragma unroll
            for (int pt = 0; pt < 4; ++pt) {
                short8v vb = *(const short8v*)(Vs + (pt * 16 + col) * 72 + ks * 32 + 8 * g);
                acc[pt] = __builtin_amdgcn_mfma_f32_16x16x32_bf16(pa, vb, acc[pt], 0, 0, 0);
            }
        }
    }
    // ---- merge the two m-parity partial flash states ----
    __syncthreads();
    if (h == 1) {
        #pragma unroll
        for (int pt = 0; pt < 4; ++pt)
            comb[(qw * 4 + pt) * 64 + lane] = make_float4(acc[pt][0], acc[pt][1], acc[pt][2], acc[pt][3]);
        comb[1024 + (qw * 2) * 64 + lane]     = make_float4(Mr[0], Mr[1], Mr[2], Mr[3]);
        comb[1024 + (qw * 2 + 1) * 64 + lane] = make_float4(Sr[0], Sr[1], Sr[2], Sr[3]);
    }
    __syncthreads();
    if (h == 0) {
        float4 m2 = comb[1024 + (qw * 2) * 64 + lane];
        float4 s2 = comb[1024 + (qw * 2 + 1) * 64 + lane];
        float M2[4] = {m2.x, m2.y, m2.z, m2.w};
        float S2[4] = {s2.x, s2.y, s2.z, s2.w};
        float f0[4], f1[4], inv[4];
        #pragma unroll
        for (int r = 0; r < 4; ++r) {
            float Mm = fmaxf(Mr[r], M2[r]);
            f0[r] = __expf(Mr[r] - Mm);
            f1[r] = __expf(M2[r] - Mm);
            inv[r] = 1.0f / (Sr[r] * f0[r] + S2[r] * f1[r]);
        }
        #pragma unroll
        for (int pt = 0; pt < 4; ++pt) {
            float4 a2 = comb[(qw * 4 + pt) * 64 + lane];
            float o0 = (acc[pt][0] * f0[0] + a2.x * f1[0]) * inv[0];
            float o1 = (acc[pt][1] * f0[1] + a2.y * f1[1]) * inv[1];
            float o2 = (acc[pt][2] * f0[2] + a2.z * f1[2]) * inv[2];
            float o3 = (acc[pt][3] * f0[3] + a2.w * f1[3]) * inv[3];
            // x1o stored transposed: [b][n][p]
            size_t base = ((size_t)b * N_ + n0 + qw * 16 + g * 4) * PD_ + pt * 16 + col;
            x1o[base]           = o0;
            x1o[base + PD_]     = o1;
            x1o[base + 2 * PD_] = o2;
            x1o[base + 3 * PD_] = o3;
        }
    }
}

// ---------------- SiLU + proj 1x1 conv + BN ----------------
__global__ __launch_bounds__(256) void k_proj(const float* __restrict__ x,
        const float* __restrict__ x1o, const float* __restrict__ pw,
        const float* __restrict__ bnw, const float* __restrict__ bnb,
        const float* __restrict__ rm,  const float* __restrict__ rv,
        float* __restrict__ out) {
    __shared__ float ys[64 * 68];          // [nn][cc] pitch 68
    __shared__ float wl[64 * 68];          // [oo][cc] pitch 68
    const int t  = threadIdx.x;
    const int nt = blockIdx.x & 255;
    const int o0 = (blockIdx.x >> 8) << 6;
    const int b  = nt >> 6;
    const int n0 = (nt & 63) << 6;
    const int nn = t & 63, og = t >> 6;
    float acc[16];
    #pragma unroll
    for (int k = 0; k < 16; ++k) acc[k] = 0.f;

    for (int c0 = 0; c0 < C_; c0 += 64) {
        __syncthreads();
        if (c0 == 0) {                     // x1o is [b][n][64p]
            #pragma unroll
            for (int i = 0; i < 16; ++i) {
                int idx = t + i * 256;
                int ln = idx >> 6, cc = idx & 63;
                float v = x1o[((size_t)b * N_ + n0 + ln) * PD_ + cc];
                v = v / (1.0f + __expf(-v));
                ys[ln * 68 + cc] = v;
            }
        } else {
            #pragma unroll
            for (int i = 0; i < 16; ++i) {
                int idx = t + i * 256;
                int cc = idx >> 6, ln = idx & 63;
                int cg = c0 + cc;
                float v = x[(size_t)(b * C_ + cg) * N_ + n0 + ln];
                v = v / (1.0f + __expf(-v));
                ys[ln * 68 + cc] = v;
            }
        }
        #pragma unroll
        for (int i = 0; i < 16; ++i) {     // stage w tile 64o x 64c
            int idx = t + i * 256;
            int oo = idx >> 6, cc = idx & 63;
            wl[oo * 68 + cc] = pw[(size_t)(o0 + oo) * C_ + c0 + cc];
        }
        __syncthreads();
        const float4* yr = (const float4*)&ys[nn * 68];
        #pragma unroll
        for (int c4 = 0; c4 < 16; ++c4) {
            float4 yv = yr[c4];
            #pragma unroll
            for (int k = 0; k < 16; ++k) {
                float4 wv = ((const float4*)&wl[(og * 16 + k) * 68])[c4];
                acc[k] += yv.x*wv.x + yv.y*wv.y + yv.z*wv.z + yv.w*wv.w;
            }
        }
    }
    #pragma unroll
    for (int k = 0; k < 16; ++k) {
        const int o = o0 + og * 16 + k;
        float inv  = bnw[o] * rsqrtf(rv[o] + EPS_);
        float beta = bnb[o] - rm[o] * inv;
        out[(size_t)(b * C_ + o) * N_ + n0 + nn] = acc[k] * inv + beta;
    }
}

extern "C" void kernel_launch(void* const* d_in, const int* in_sizes, int n_in,
                              void* d_out, int out_size, void* d_ws, size_t ws_size,
                              hipStream_t stream) {
    const float* x   = (const float*)d_in[0];
    const float* gnw = (const float*)d_in[1];
    const float* gnb = (const float*)d_in[2];
    const float* qw  = (const float*)d_in[3];
    const float* qbw = (const float*)d_in[4];
    const float* qbb = (const float*)d_in[5];
    const float* qrm = (const float*)d_in[6];
    const float* qrv = (const float*)d_in[7];
    const float* pw  = (const float*)d_in[8];
    const float* pbw = (const float*)d_in[9];
    const float* pbb = (const float*)d_in[10];
    const float* prm = (const float*)d_in[11];
    const float* prv = (const float*)d_in[12];
    float* out = (float*)d_out;
    char* wsb = (char*)d_ws;

    float* part  = (float*)wsb;                          // 2 KB
    float* stats = (float*)(wsb + 2048);                 // 32 B
    short* qkvb  = (short*)(wsb + 4096);                 // 4*96*4096*2 = 3 MB
    float* x1o   = (float*)(wsb + 4096 + (size_t)B_ * O96_ * N_ * 2);  // [b][n][64] 4 MB

    k_gn_part<<<256, 256, 0, stream>>>(x, part);
    k_gn_fin<<<4, 64, 0, stream>>>(part, stats);
    k_qkv<<<256, 256, 0, stream>>>(x, gnw, gnb, qw, qbw, qbb, qrm, qrv, stats, qkvb);
    k_attn<<<256, 512, 0, stream>>>(qkvb, x1o);
    k_proj<<<1024, 256, 0, stream>>>(x, x1o, pw, pbw, pbb, prm, prv, out);
}

// Round 4
// 123.720 us; speedup vs baseline: 5.3425x; 1.9899x over previous
//
#include <hip/hip_runtime.h>
#include <math.h>

static constexpr int B_ = 4;
static constexpr int C_ = 256;
static constexpr int PD_ = 64;
static constexpr int N_ = 4096;
static constexpr int O96_ = 96;
static constexpr float EPS_ = 1e-5f;
static constexpr float SCALE_ = 0.25f;   // 16^-0.5

typedef __attribute__((ext_vector_type(8))) short short8v;
typedef __attribute__((ext_vector_type(4))) float f32x4;

__device__ inline short f2bf(float x) {
    union { float f; unsigned u; } v; v.f = x;
    unsigned r = v.u + 0x7FFF + ((v.u >> 16) & 1);   // RNE
    return (short)(r >> 16);
}
__device__ inline float silu_(float v) { return v / (1.0f + __expf(-v)); }

// ---------------- GroupNorm: per-(b,c) partial sums ----------------
__global__ __launch_bounds__(256) void k_gn_part(const float* __restrict__ x,
                                                 float* __restrict__ part) {
    const int blk = blockIdx.x;            // b*64 + c
    const int b = blk >> 6, c = blk & 63;
    const float* p = x + (size_t)(b * C_ + c) * N_;
    float s = 0.f, q = 0.f;
    for (int i = threadIdx.x; i < N_; i += 256) {
        float v = p[i]; s += v; q += v * v;
    }
    for (int d = 1; d < 64; d <<= 1) {
        s += __shfl_xor(s, d, 64);
        q += __shfl_xor(q, d, 64);
    }
    __shared__ float ls[4], lq[4];
    const int lane = threadIdx.x & 63, wid = threadIdx.x >> 6;
    if (lane == 0) { ls[wid] = s; lq[wid] = q; }
    __syncthreads();
    if (threadIdx.x == 0) {
        part[2 * blk]     = ls[0] + ls[1] + ls[2] + ls[3];
        part[2 * blk + 1] = lq[0] + lq[1] + lq[2] + lq[3];
    }
}

// ---------------- GroupNorm: finalize mean/rstd per batch ----------------
__global__ __launch_bounds__(64) void k_gn_fin(const float* __restrict__ part,
                                               float* __restrict__ stats) {
    const int b = blockIdx.x;
    float s = part[2 * (b * 64 + threadIdx.x)];
    float q = part[2 * (b * 64 + threadIdx.x) + 1];
    for (int d = 1; d < 64; d <<= 1) {
        s += __shfl_xor(s, d, 64);
        q += __shfl_xor(q, d, 64);
    }
    if (threadIdx.x == 0) {
        const float inv_n = 1.0f / (float)(PD_ * N_);
        float mu = s * inv_n;
        float var = q * inv_n - mu * mu;
        stats[2 * b]     = mu;
        stats[2 * b + 1] = rsqrtf(var + EPS_);
    }
}

// ------- proj weight -> bf16 with BN scale folded; beta kept fp32 -------
__global__ __launch_bounds__(256) void k_wcvt(const float* __restrict__ pw,
        const float* __restrict__ bnw, const float* __restrict__ bnb,
        const float* __restrict__ rm,  const float* __restrict__ rv,
        short* __restrict__ wbf, float* __restrict__ beta) {
    const int idx = blockIdx.x * 256 + threadIdx.x;   // 0..65535
    const int o = idx >> 8, c = idx & 255;
    const float inv = bnw[o] * rsqrtf(rv[o] + EPS_);
    wbf[idx] = f2bf(pw[idx] * inv);
    if (c == 0) beta[o] = bnb[o] - rm[o] * inv;
}

// ------- fused GN-apply + QKV 1x1 conv + BN -> bf16 (scale folded into q) -------
__global__ __launch_bounds__(256) void k_qkv(const float* __restrict__ x,
        const float* __restrict__ gnw, const float* __restrict__ gnb,
        const float* __restrict__ qw,  const float* __restrict__ bnw,
        const float* __restrict__ bnb, const float* __restrict__ rm,
        const float* __restrict__ rv,  const float* __restrict__ stats,
        short* __restrict__ qkvb) {
    __shared__ float wl[O96_ * PD_];
    __shared__ float binv[O96_], bbeta[O96_];
    const int t = threadIdx.x;
    const int b = blockIdx.x >> 6;
    const int n0 = (blockIdx.x & 63) << 6;
    for (int i = t; i < O96_ * PD_; i += 256) wl[i] = qw[i];
    for (int o = t; o < O96_; o += 256) {
        float inv  = bnw[o] * rsqrtf(rv[o] + EPS_);
        float beta = bnb[o] - rm[o] * inv;
        if (o < 16) { inv *= SCALE_; beta *= SCALE_; }
        binv[o] = inv; bbeta[o] = beta;
    }
    const float mu = stats[2 * b], rs = stats[2 * b + 1];
    __syncthreads();
    const int n  = n0 + (t & 63);
    const int og = t >> 6;                  // 0..3, splits the 96 outputs
    float xn[PD_];
    const float* xb = x + (size_t)b * C_ * N_ + n;
    #pragma unroll
    for (int c = 0; c < PD_; ++c)
        xn[c] = (xb[(size_t)c * N_] - mu) * rs * gnw[c] + gnb[c];
    short* qb = qkvb + (size_t)b * O96_ * N_ + n;
    for (int o = og * 24; o < og * 24 + 24; ++o) {
        const float4* wr = (const float4*)&wl[o * PD_];
        float a = 0.f;
        #pragma unroll
        for (int c4 = 0; c4 < 16; ++c4) {
            float4 w4 = wr[c4];
            a += w4.x * xn[4*c4] + w4.y * xn[4*c4+1] + w4.z * xn[4*c4+2] + w4.w * xn[4*c4+3];
        }
        qb[(size_t)o * N_] = f2bf(a * binv[o] + bbeta[o]);
    }
}

// ---------------- MFMA flash attention ----------------
// 64-q tile/block, 8 waves: waves 0-3 = even m-chunks, 4-7 = odd m-chunks.
// Epilogue: silu + bf16 into yall[b][n][0..64].
__global__ __launch_bounds__(512) void k_attn(const short* __restrict__ qkvb,
                                              short* __restrict__ yall) {
    __shared__ __align__(16) char smem[46080];
    short* Qt     = (short*)smem;             // [64][24]
    short* KtBase = (short*)(smem + 3072);    // [2][64][24]
    short* VsBase = (short*)(smem + 9216);    // [2][64][72]
    short* PlBase = (short*)(smem + 27648);   // [8][16][72]
    float4* comb  = (float4*)(smem + 3072);   // overlay after loop: acc[16][64], ms[8][64]

    const int t    = threadIdx.x;
    const int b    = blockIdx.x >> 6;
    const int n0   = (blockIdx.x & 63) << 6;
    const int w    = t >> 6;
    const int lane = t & 63;
    const int qw   = w & 3;       // q sub-tile (16 rows)
    const int h    = w >> 2;      // m-parity group
    const int tg   = t & 255;
    const int g    = lane >> 4;   // 0..3
    const int col  = lane & 15;

    const short* qb = qkvb + (size_t)b * O96_ * N_;
    short* Kt = KtBase + h * 1536;
    short* Vs = VsBase + h * 4608;
    short* Pl = PlBase + w * 1152;

    // stage Q^T [q][c] once (bf16, scale pre-folded)
    #pragma unroll
    for (int i = 0; i < 2; ++i) {
        int idx = t + i * 512;
        int c = idx >> 6, q = idx & 63;
        Qt[q * 24 + c] = qb[(size_t)c * N_ + n0 + q];
    }

    f32x4 acc[4];
    #pragma unroll
    for (int pt = 0; pt < 4; ++pt) acc[pt] = 0.f;
    float Mr[4] = {-INFINITY, -INFINITY, -INFINITY, -INFINITY};
    float Sr[4] = {0.f, 0.f, 0.f, 0.f};
    short8v a_q = 0;

    for (int it = 0; it < 32; ++it) {
        const int m0 = (it * 2 + h) << 6;
        __syncthreads();
        // stage K chunk 16c x 64m -> Kt[m][c]
        #pragma unroll
        for (int i = 0; i < 4; ++i) {
            int idx = tg + i * 256;
            int c = idx >> 6, m = idx & 63;
            Kt[m * 24 + c] = qb[(size_t)(16 + c) * N_ + m0 + m];
        }
        // stage V chunk 64p x 64m -> Vs[p][m] (natural), short4
        #pragma unroll
        for (int i = 0; i < 4; ++i) {
            int idx = tg + i * 256;
            int p = idx >> 4, m4 = idx & 15;
            short4 v4 = *(const short4*)(qb + (size_t)(32 + p) * N_ + m0 + m4 * 4);
            *(short4*)(Vs + p * 72 + m4 * 4) = v4;
        }
        __syncthreads();
        if (it == 0) {
            if (g < 2) a_q = *(const short8v*)(Qt + (qw * 16 + col) * 24 + 8 * g);
        }
        // ---- QK^T: S[16q x 64m], K-dim c=16 zero-padded to 32 ----
        f32x4 s[4];
        #pragma unroll
        for (int mt = 0; mt < 4; ++mt) {
            short8v kb = 0;
            if (g < 2) kb = *(const short8v*)(Kt + (mt * 16 + col) * 24 + 8 * g);
            f32x4 z = 0.f;
            s[mt] = __builtin_amdgcn_mfma_f32_16x16x32_bf16(a_q, kb, z, 0, 0, 0);
        }
        // ---- online softmax (rows live in 16-lane groups) ----
        float f_[4];
        #pragma unroll
        for (int r = 0; r < 4; ++r) {
            float mx = fmaxf(fmaxf(s[0][r], s[1][r]), fmaxf(s[2][r], s[3][r]));
            mx = fmaxf(mx, __shfl_xor(mx, 1, 64));
            mx = fmaxf(mx, __shfl_xor(mx, 2, 64));
            mx = fmaxf(mx, __shfl_xor(mx, 4, 64));
            mx = fmaxf(mx, __shfl_xor(mx, 8, 64));
            float Mn = fmaxf(Mr[r], mx);
            f_[r] = __expf(Mr[r] - Mn);
            Mr[r] = Mn;
            float p0 = __expf(s[0][r] - Mn), p1 = __expf(s[1][r] - Mn);
            float p2 = __expf(s[2][r] - Mn), p3 = __expf(s[3][r] - Mn);
            s[0][r] = p0; s[1][r] = p1; s[2][r] = p2; s[3][r] = p3;
            float ps = p0 + p1 + p2 + p3;
            ps += __shfl_xor(ps, 1, 64);
            ps += __shfl_xor(ps, 2, 64);
            ps += __shfl_xor(ps, 4, 64);
            ps += __shfl_xor(ps, 8, 64);
            Sr[r] = Sr[r] * f_[r] + ps;
        }
        // ---- P -> bf16 -> wave-private LDS [16q][64m] pitch 72 ----
        #pragma unroll
        for (int mt = 0; mt < 4; ++mt)
            #pragma unroll
            for (int r = 0; r < 4; ++r)
                Pl[(g * 4 + r) * 72 + mt * 16 + col] = f2bf(s[mt][r]);
        // Cross-lane LDS handoff within the wave: drain ds_writes before
        // any lane's ds_read (guide rule #18).
        asm volatile("s_waitcnt lgkmcnt(0)" ::: "memory");
        __builtin_amdgcn_sched_barrier(0);
        // ---- rescale acc, then PV: O^T[16q x 64p] += P[16x64] * V^T[64x64p] ----
        #pragma unroll
        for (int pt = 0; pt < 4; ++pt)
            #pragma unroll
            for (int r = 0; r < 4; ++r)
                acc[pt][r] *= f_[r];
        #pragma unroll
        for (int ks = 0; ks < 2; ++ks) {
            short8v pa = *(const short8v*)(Pl + col * 72 + ks * 32 + 8 * g);
            #pragma unroll
            for (int pt = 0; pt < 4; ++pt) {
                short8v vb = *(const short8v*)(Vs + (pt * 16 + col) * 72 + ks * 32 + 8 * g);
                acc[pt] = __builtin_amdgcn_mfma_f32_16x16x32_bf16(pa, vb, acc[pt], 0, 0, 0);
            }
        }
    }
    // ---- merge the two m-parity partial flash states ----
    __syncthreads();
    if (h == 1) {
        #pragma unroll
        for (int pt = 0; pt < 4; ++pt)
            comb[(qw * 4 + pt) * 64 + lane] = make_float4(acc[pt][0], acc[pt][1], acc[pt][2], acc[pt][3]);
        comb[1024 + (qw * 2) * 64 + lane]     = make_float4(Mr[0], Mr[1], Mr[2], Mr[3]);
        comb[1024 + (qw * 2 + 1) * 64 + lane] = make_float4(Sr[0], Sr[1], Sr[2], Sr[3]);
    }
    __syncthreads();
    if (h == 0) {
        float4 m2 = comb[1024 + (qw * 2) * 64 + lane];
        float4 s2 = comb[1024 + (qw * 2 + 1) * 64 + lane];
        float M2[4] = {m2.x, m2.y, m2.z, m2.w};
        float S2[4] = {s2.x, s2.y, s2.z, s2.w};
        float f0[4], f1[4], inv[4];
        #pragma unroll
        for (int r = 0; r < 4; ++r) {
            float Mm = fmaxf(Mr[r], M2[r]);
            f0[r] = __expf(Mr[r] - Mm);
            f1[r] = __expf(M2[r] - Mm);
            inv[r] = 1.0f / (Sr[r] * f0[r] + S2[r] * f1[r]);
        }
        #pragma unroll
        for (int pt = 0; pt < 4; ++pt) {
            float4 a2 = comb[(qw * 4 + pt) * 64 + lane];
            float o0 = (acc[pt][0] * f0[0] + a2.x * f1[0]) * inv[0];
            float o1 = (acc[pt][1] * f0[1] + a2.y * f1[1]) * inv[1];
            float o2 = (acc[pt][2] * f0[2] + a2.z * f1[2]) * inv[2];
            float o3 = (acc[pt][3] * f0[3] + a2.w * f1[3]) * inv[3];
            // yall[b][n][c]: silu + bf16, channels 0..63
            size_t base = ((size_t)b * N_ + n0 + qw * 16 + g * 4) * 256 + pt * 16 + col;
            yall[base]           = f2bf(silu_(o0));
            yall[base + 256]     = f2bf(silu_(o1));
            yall[base + 2 * 256] = f2bf(silu_(o2));
            yall[base + 3 * 256] = f2bf(silu_(o3));
        }
    }
}

// ------- x2 transpose: x[b][64..256][n] -> silu -> bf16 yall[b][n][64..256] -------
__global__ __launch_bounds__(256) void k_x2t(const float* __restrict__ x,
                                             short* __restrict__ yall) {
    __shared__ short lt[64 * 66];
    const int t  = threadIdx.x;
    const int n0 = blockIdx.x << 6;
    const int c0 = 64 + (blockIdx.y << 6);
    const int b  = blockIdx.z;
    #pragma unroll
    for (int i = 0; i < 16; ++i) {
        int idx = t + i * 256;
        int cr = idx >> 6, nn = idx & 63;
        float v = x[((size_t)(b * C_ + c0 + cr)) * N_ + n0 + nn];
        lt[cr * 66 + nn] = f2bf(silu_(v));
    }
    __syncthreads();
    #pragma unroll
    for (int i = 0; i < 16; ++i) {
        int idx = t + i * 256;
        int nn = idx >> 6, cc = idx & 63;
        yall[((size_t)b * N_ + n0 + nn) * 256 + c0 + cc] = lt[cc * 66 + nn];
    }
}

// ---------------- proj: bf16 MFMA GEMM, fragments direct from global ----------------
// out[b][o][n] = sum_c wbf[o][c] * yall[b][n][c] + beta[o]
// wave tile 32o x 32n; block 4 waves (64o x 64n); grid (64 n-tiles, 4 o-tiles, 4 b)
__global__ __launch_bounds__(256) void k_proj(const short* __restrict__ yall,
        const short* __restrict__ wbf, const float* __restrict__ beta,
        float* __restrict__ out) {
    const int t = threadIdx.x;
    const int w = t >> 6, lane = t & 63;
    const int col = lane & 15, g = lane >> 4;
    const int b = blockIdx.z;
    const int o_base = (blockIdx.y << 6) + (w >> 1) * 32;
    const int n_base = (blockIdx.x << 6) + (w & 1) * 32;
    const short* pa = wbf + (o_base + col) * C_ + g * 8;
    const short* pb = yall + ((size_t)b * N_ + n_base + col) * C_ + g * 8;
    f32x4 acc00 = 0.f, acc01 = 0.f, acc10 = 0.f, acc11 = 0.f;
    #pragma unroll
    for (int kk = 0; kk < 8; ++kk) {
        short8v a0 = *(const short8v*)(pa + kk * 32);
        short8v a1 = *(const short8v*)(pa + 16 * C_ + kk * 32);
        short8v b0 = *(const short8v*)(pb + kk * 32);
        short8v b1 = *(const short8v*)(pb + 16 * C_ + kk * 32);
        acc00 = __builtin_amdgcn_mfma_f32_16x16x32_bf16(a0, b0, acc00, 0, 0, 0);
        acc01 = __builtin_amdgcn_mfma_f32_16x16x32_bf16(a0, b1, acc01, 0, 0, 0);
        acc10 = __builtin_amdgcn_mfma_f32_16x16x32_bf16(a1, b0, acc10, 0, 0, 0);
        acc11 = __builtin_amdgcn_mfma_f32_16x16x32_bf16(a1, b1, acc11, 0, 0, 0);
    }
    #pragma unroll
    for (int i = 0; i < 2; ++i) {
        const int o0 = o_base + i * 16 + g * 4;
        const f32x4 aj0 = i ? acc10 : acc00;
        const f32x4 aj1 = i ? acc11 : acc01;
        #pragma unroll
        for (int r = 0; r < 4; ++r) {
            const float be = beta[o0 + r];
            float* po = out + ((size_t)(b * C_ + o0 + r)) * N_ + n_base + col;
            po[0]  = aj0[r] + be;
            po[16] = aj1[r] + be;
        }
    }
}

extern "C" void kernel_launch(void* const* d_in, const int* in_sizes, int n_in,
                              void* d_out, int out_size, void* d_ws, size_t ws_size,
                              hipStream_t stream) {
    const float* x   = (const float*)d_in[0];
    const float* gnw = (const float*)d_in[1];
    const float* gnb = (const float*)d_in[2];
    const float* qw  = (const float*)d_in[3];
    const float* qbw = (const float*)d_in[4];
    const float* qbb = (const float*)d_in[5];
    const float* qrm = (const float*)d_in[6];
    const float* qrv = (const float*)d_in[7];
    const float* pw  = (const float*)d_in[8];
    const float* pbw = (const float*)d_in[9];
    const float* pbb = (const float*)d_in[10];
    const float* prm = (const float*)d_in[11];
    const float* prv = (const float*)d_in[12];
    float* out = (float*)d_out;
    char* wsb = (char*)d_ws;

    float* part  = (float*)wsb;                                   // 2 KB
    float* stats = (float*)(wsb + 2048);                          // 32 B
    short* qkvb  = (short*)(wsb + 4096);                          // 3 MB
    short* yall  = (short*)(wsb + 4096 + 3145728);                // [4][4096][256] bf16, 8 MB
    short* wbf   = (short*)(wsb + 4096 + 3145728 + 8388608);      // 128 KB
    float* beta  = (float*)(wsb + 4096 + 3145728 + 8388608 + 131072);  // 1 KB

    k_gn_part<<<256, 256, 0, stream>>>(x, part);
    k_gn_fin<<<4, 64, 0, stream>>>(part, stats);
    k_wcvt<<<256, 256, 0, stream>>>(pw, pbw, pbb, prm, prv, wbf, beta);
    k_qkv<<<256, 256, 0, stream>>>(x, gnw, gnb, qw, qbw, qbb, qrm, qrv, stats, qkvb);
    k_attn<<<256, 512, 0, stream>>>(qkvb, yall);
    k_x2t<<<dim3(64, 3, 4), 256, 0, stream>>>(x, yall);
    k_proj<<<dim3(64, 4, 4), 256, 0, stream>>>(yall, wbf, beta, out);
}

// Round 5
// 108.157 us; speedup vs baseline: 6.1113x; 1.1439x over previous
//
#include <hip/hip_runtime.h>
#include <math.h>

static constexpr int B_ = 4;
static constexpr int C_ = 256;
static constexpr int PD_ = 64;
static constexpr int N_ = 4096;
static constexpr int O96_ = 96;
static constexpr float EPS_ = 1e-5f;
static constexpr float SCALE_ = 0.25f;   // 16^-0.5

typedef __attribute__((ext_vector_type(8))) short short8v;
typedef __attribute__((ext_vector_type(4))) float f32x4;

__device__ inline short f2bf(float x) {
    union { float f; unsigned u; } v; v.f = x;
    unsigned r = v.u + 0x7FFF + ((v.u >> 16) & 1);   // RNE
    return (short)(r >> 16);
}
__device__ inline float bf2f(short s) {
    union { float f; unsigned u; } v; v.u = ((unsigned)(unsigned short)s) << 16;
    return v.f;
}
__device__ inline float silu_(float v) { return v / (1.0f + __expf(-v)); }

// ---------------- GroupNorm: per-(b,c) partial sums ----------------
__global__ __launch_bounds__(256) void k_gn_part(const float* __restrict__ x,
                                                 float* __restrict__ part) {
    const int blk = blockIdx.x;            // b*64 + c
    const int b = blk >> 6, c = blk & 63;
    const float* p = x + (size_t)(b * C_ + c) * N_;
    float s = 0.f, q = 0.f;
    for (int i = threadIdx.x; i < N_; i += 256) {
        float v = p[i]; s += v; q += v * v;
    }
    for (int d = 1; d < 64; d <<= 1) {
        s += __shfl_xor(s, d, 64);
        q += __shfl_xor(q, d, 64);
    }
    __shared__ float ls[4], lq[4];
    const int lane = threadIdx.x & 63, wid = threadIdx.x >> 6;
    if (lane == 0) { ls[wid] = s; lq[wid] = q; }
    __syncthreads();
    if (threadIdx.x == 0) {
        part[2 * blk]     = ls[0] + ls[1] + ls[2] + ls[3];
        part[2 * blk + 1] = lq[0] + lq[1] + lq[2] + lq[3];
    }
}

// ---------------- GroupNorm: finalize mean/rstd per batch ----------------
__global__ __launch_bounds__(64) void k_gn_fin(const float* __restrict__ part,
                                               float* __restrict__ stats) {
    const int b = blockIdx.x;
    float s = part[2 * (b * 64 + threadIdx.x)];
    float q = part[2 * (b * 64 + threadIdx.x) + 1];
    for (int d = 1; d < 64; d <<= 1) {
        s += __shfl_xor(s, d, 64);
        q += __shfl_xor(q, d, 64);
    }
    if (threadIdx.x == 0) {
        const float inv_n = 1.0f / (float)(PD_ * N_);
        float mu = s * inv_n;
        float var = q * inv_n - mu * mu;
        stats[2 * b]     = mu;
        stats[2 * b + 1] = rsqrtf(var + EPS_);
    }
}

// ------- proj weight -> bf16 with BN scale folded; beta kept fp32 -------
__global__ __launch_bounds__(256) void k_wcvt(const float* __restrict__ pw,
        const float* __restrict__ bnw, const float* __restrict__ bnb,
        const float* __restrict__ rm,  const float* __restrict__ rv,
        short* __restrict__ wbf, float* __restrict__ beta) {
    const int idx = blockIdx.x * 256 + threadIdx.x;   // 0..65535
    const int o = idx >> 8, c = idx & 255;
    const float inv = bnw[o] * rsqrtf(rv[o] + EPS_);
    wbf[idx] = f2bf(pw[idx] * inv);
    if (c == 0) beta[o] = bnb[o] - rm[o] * inv;
}

// ------- fused GN-apply + QKV 1x1 conv + BN -> bf16 (scale folded into q) -------
__global__ __launch_bounds__(256) void k_qkv(const float* __restrict__ x,
        const float* __restrict__ gnw, const float* __restrict__ gnb,
        const float* __restrict__ qw,  const float* __restrict__ bnw,
        const float* __restrict__ bnb, const float* __restrict__ rm,
        const float* __restrict__ rv,  const float* __restrict__ stats,
        short* __restrict__ qkvb) {
    __shared__ float wl[O96_ * PD_];
    __shared__ float binv[O96_], bbeta[O96_];
    const int t = threadIdx.x;
    const int b = blockIdx.x >> 6;
    const int n0 = (blockIdx.x & 63) << 6;
    for (int i = t; i < O96_ * PD_; i += 256) wl[i] = qw[i];
    for (int o = t; o < O96_; o += 256) {
        float inv  = bnw[o] * rsqrtf(rv[o] + EPS_);
        float beta = bnb[o] - rm[o] * inv;
        if (o < 16) { inv *= SCALE_; beta *= SCALE_; }
        binv[o] = inv; bbeta[o] = beta;
    }
    const float mu = stats[2 * b], rs = stats[2 * b + 1];
    __syncthreads();
    const int n  = n0 + (t & 63);
    const int og = t >> 6;                  // 0..3, splits the 96 outputs
    float xn[PD_];
    const float* xb = x + (size_t)b * C_ * N_ + n;
    #pragma unroll
    for (int c = 0; c < PD_; ++c)
        xn[c] = (xb[(size_t)c * N_] - mu) * rs * gnw[c] + gnb[c];
    short* qb = qkvb + (size_t)b * O96_ * N_ + n;
    for (int o = og * 24; o < og * 24 + 24; ++o) {
        const float4* wr = (const float4*)&wl[o * PD_];
        float a = 0.f;
        #pragma unroll
        for (int c4 = 0; c4 < 16; ++c4) {
            float4 w4 = wr[c4];
            a += w4.x * xn[4*c4] + w4.y * xn[4*c4+1] + w4.z * xn[4*c4+2] + w4.w * xn[4*c4+3];
        }
        qb[(size_t)o * N_] = f2bf(a * binv[o] + bbeta[o]);
    }
}

// ---------------- MFMA flash attention (m-split partials) ----------------
// grid 512 = (b, mh, ntile) XCD-swizzled; 8 waves: qw 0..3 x h 0..1.
// Block handles m-chunks [mh*32, mh*32+32); writes unnormalized bf16 O + M,S.
__global__ __launch_bounds__(512) void k_attn(const short* __restrict__ qkvb,
                                              short* __restrict__ apart) {
    __shared__ __align__(16) char smem[46080];
    short* Qt     = (short*)smem;             // [64][24]
    short* KtBase = (short*)(smem + 3072);    // [2][64][24]
    short* VsBase = (short*)(smem + 9216);    // [2][64][72]
    short* PlBase = (short*)(smem + 27648);   // [8][16][72]
    float4* comb  = (float4*)(smem + 3072);   // overlay after loop: acc[16][64], ms[8][64]

    // XCD-aware swizzle: consecutive wg round-robin XCDs; give each XCD one
    // contiguous (b,mh) group of 64 ntiles so its L2 holds ONE batch's K/V half.
    const int wg  = blockIdx.x;
    const int swz = (wg & 7) * 64 + (wg >> 3);
    const int b   = swz >> 7;
    const int mh  = (swz >> 6) & 1;
    const int n0  = (swz & 63) << 6;

    const int t    = threadIdx.x;
    const int w    = t >> 6;
    const int lane = t & 63;
    const int qw   = w & 3;       // q sub-tile (16 rows)
    const int h    = w >> 2;      // m-parity group
    const int tg   = t & 255;
    const int g    = lane >> 4;   // 0..3
    const int col  = lane & 15;

    const short* qb = qkvb + (size_t)b * O96_ * N_;
    short* Kt = KtBase + h * 1536;
    short* Vs = VsBase + h * 4608;
    short* Pl = PlBase + w * 1152;

    // stage Q^T [q][c] once (bf16, scale pre-folded)
    #pragma unroll
    for (int i = 0; i < 2; ++i) {
        int idx = t + i * 512;
        int c = idx >> 6, q = idx & 63;
        Qt[q * 24 + c] = qb[(size_t)c * N_ + n0 + q];
    }

    f32x4 acc[4];
    #pragma unroll
    for (int pt = 0; pt < 4; ++pt) acc[pt] = 0.f;
    float Mr[4] = {-INFINITY, -INFINITY, -INFINITY, -INFINITY};
    float Sr[4] = {0.f, 0.f, 0.f, 0.f};
    short8v a_q = 0;

    for (int it = 0; it < 16; ++it) {
        const int m0 = (mh * 32 + it * 2 + h) << 6;
        __syncthreads();
        // stage K chunk 16c x 64m -> Kt[m][c], b32 writes (c-pairs), 2-way banks
        #pragma unroll
        for (int i = 0; i < 2; ++i) {
            int idx = tg + i * 256;
            int mlow = idx & 15, cp = (idx >> 4) & 7, mh2 = idx >> 7;
            int m = mh2 * 16 + mlow, c0 = cp * 2;
            unsigned short v0 = (unsigned short)qb[(size_t)(16 + c0) * N_ + m0 + m];
            unsigned short v1 = (unsigned short)qb[(size_t)(17 + c0) * N_ + m0 + m];
            *(unsigned*)(Kt + m * 24 + c0) = (unsigned)v0 | ((unsigned)v1 << 16);
        }
        // stage V chunk 64p x 64m -> Vs[p][m] (natural), short4
        #pragma unroll
        for (int i = 0; i < 4; ++i) {
            int idx = tg + i * 256;
            int p = idx >> 4, m4 = idx & 15;
            short4 v4 = *(const short4*)(qb + (size_t)(32 + p) * N_ + m0 + m4 * 4);
            *(short4*)(Vs + p * 72 + m4 * 4) = v4;
        }
        __syncthreads();
        if (it == 0) {
            if (g < 2) a_q = *(const short8v*)(Qt + (qw * 16 + col) * 24 + 8 * g);
        }
        // ---- QK^T: S[16q x 64m], K-dim c=16 zero-padded to 32 ----
        f32x4 s[4];
        #pragma unroll
        for (int mt = 0; mt < 4; ++mt) {
            short8v kb = 0;
            if (g < 2) kb = *(const short8v*)(Kt + (mt * 16 + col) * 24 + 8 * g);
            f32x4 z = 0.f;
            s[mt] = __builtin_amdgcn_mfma_f32_16x16x32_bf16(a_q, kb, z, 0, 0, 0);
        }
        // ---- online softmax (rows live in 16-lane groups) ----
        float f_[4];
        #pragma unroll
        for (int r = 0; r < 4; ++r) {
            float mx = fmaxf(fmaxf(s[0][r], s[1][r]), fmaxf(s[2][r], s[3][r]));
            mx = fmaxf(mx, __shfl_xor(mx, 1, 64));
            mx = fmaxf(mx, __shfl_xor(mx, 2, 64));
            mx = fmaxf(mx, __shfl_xor(mx, 4, 64));
            mx = fmaxf(mx, __shfl_xor(mx, 8, 64));
            float Mn = fmaxf(Mr[r], mx);
            f_[r] = __expf(Mr[r] - Mn);
            Mr[r] = Mn;
            float p0 = __expf(s[0][r] - Mn), p1 = __expf(s[1][r] - Mn);
            float p2 = __expf(s[2][r] - Mn), p3 = __expf(s[3][r] - Mn);
            s[0][r] = p0; s[1][r] = p1; s[2][r] = p2; s[3][r] = p3;
            float ps = p0 + p1 + p2 + p3;
            ps += __shfl_xor(ps, 1, 64);
            ps += __shfl_xor(ps, 2, 64);
            ps += __shfl_xor(ps, 4, 64);
            ps += __shfl_xor(ps, 8, 64);
            Sr[r] = Sr[r] * f_[r] + ps;
        }
        // ---- P -> bf16 -> wave-private LDS [16q][64m] pitch 72 ----
        #pragma unroll
        for (int mt = 0; mt < 4; ++mt)
            #pragma unroll
            for (int r = 0; r < 4; ++r)
                Pl[(g * 4 + r) * 72 + mt * 16 + col] = f2bf(s[mt][r]);
        // Cross-lane LDS handoff within the wave: drain ds_writes before
        // any lane's ds_read (guide rule #18).
        asm volatile("s_waitcnt lgkmcnt(0)" ::: "memory");
        __builtin_amdgcn_sched_barrier(0);
        // ---- rescale acc, then PV: O^T[16q x 64p] += P[16x64] * V^T[64x64p] ----
        #pragma unroll
        for (int pt = 0; pt < 4; ++pt)
            #pragma unroll
            for (int r = 0; r < 4; ++r)
                acc[pt][r] *= f_[r];
        #pragma unroll
        for (int ks = 0; ks < 2; ++ks) {
            short8v pa = *(const short8v*)(Pl + col * 72 + ks * 32 + 8 * g);
            #pragma unroll
            for (int pt = 0; pt < 4; ++pt) {
                short8v vb = *(const short8v*)(Vs + (pt * 16 + col) * 72 + ks * 32 + 8 * g);
                acc[pt] = __builtin_amdgcn_mfma_f32_16x16x32_bf16(pa, vb, acc[pt], 0, 0, 0);
            }
        }
    }
    // ---- merge the two m-parity partial flash states; emit block partial ----
    __syncthreads();
    if (h == 1) {
        #pragma unroll
        for (int pt = 0; pt < 4; ++pt)
            comb[(qw * 4 + pt) * 64 + lane] = make_float4(acc[pt][0], acc[pt][1], acc[pt][2], acc[pt][3]);
        comb[1024 + (qw * 2) * 64 + lane]     = make_float4(Mr[0], Mr[1], Mr[2], Mr[3]);
        comb[1024 + (qw * 2 + 1) * 64 + lane] = make_float4(Sr[0], Sr[1], Sr[2], Sr[3]);
    }
    __syncthreads();
    if (h == 0) {
        float4 m2 = comb[1024 + (qw * 2) * 64 + lane];
        float4 s2 = comb[1024 + (qw * 2 + 1) * 64 + lane];
        float M2[4] = {m2.x, m2.y, m2.z, m2.w};
        float S2[4] = {s2.x, s2.y, s2.z, s2.w};
        float f0[4], f1[4], Mm[4], Sm[4];
        #pragma unroll
        for (int r = 0; r < 4; ++r) {
            Mm[r] = fmaxf(Mr[r], M2[r]);
            f0[r] = __expf(Mr[r] - Mm[r]);
            f1[r] = __expf(M2[r] - Mm[r]);
            Sm[r] = Sr[r] * f0[r] + S2[r] * f1[r];
        }
        // partial slot: [64q][64p] bf16 O (unnormalized), then M[64],S[64] f32
        short* po = apart + (size_t)((b * 2 + mh) * 64 + (n0 >> 6)) * 4352;
        #pragma unroll
        for (int pt = 0; pt < 4; ++pt) {
            float4 a2 = comb[(qw * 4 + pt) * 64 + lane];
            po[(qw * 16 + g * 4 + 0) * 64 + pt * 16 + col] = f2bf(acc[pt][0] * f0[0] + a2.x * f1[0]);
            po[(qw * 16 + g * 4 + 1) * 64 + pt * 16 + col] = f2bf(acc[pt][1] * f0[1] + a2.y * f1[1]);
            po[(qw * 16 + g * 4 + 2) * 64 + pt * 16 + col] = f2bf(acc[pt][2] * f0[2] + a2.z * f1[2]);
            po[(qw * 16 + g * 4 + 3) * 64 + pt * 16 + col] = f2bf(acc[pt][3] * f0[3] + a2.w * f1[3]);
        }
        if (col == 0) {
            float* ms = (float*)(po + 4096);
            #pragma unroll
            for (int r = 0; r < 4; ++r) {
                ms[qw * 16 + g * 4 + r]      = Mm[r];
                ms[64 + qw * 16 + g * 4 + r] = Sm[r];
            }
        }
    }
}

// ------- merge the 2 m-half partials -> 1/S -> silu -> bf16 yall[...,0..64) -------
__global__ __launch_bounds__(256) void k_amerge(const short* __restrict__ apart,
                                                short* __restrict__ yall) {
    const int blk = blockIdx.x;            // b*64 + nt
    const int b = blk >> 6, nt = blk & 63;
    const short* p0 = apart + (size_t)((b * 2 + 0) * 64 + nt) * 4352;
    const short* p1 = apart + (size_t)((b * 2 + 1) * 64 + nt) * 4352;
    const int t = threadIdx.x;
    const int q = t >> 2, pg = t & 3;
    const float* ms0 = (const float*)(p0 + 4096);
    const float* ms1 = (const float*)(p1 + 4096);
    const float M0 = ms0[q], S0 = ms0[64 + q];
    const float M1 = ms1[q], S1 = ms1[64 + q];
    const float Mm = fmaxf(M0, M1);
    const float e0 = __expf(M0 - Mm), e1 = __expf(M1 - Mm);
    const float inv = 1.0f / (S0 * e0 + S1 * e1);
    #pragma unroll
    for (int i = 0; i < 4; ++i) {
        const int p = pg * 16 + i * 4;
        short4 a0 = *(const short4*)(p0 + q * 64 + p);
        short4 a1 = *(const short4*)(p1 + q * 64 + p);
        short4 o;
        o.x = f2bf(silu_((bf2f(a0.x) * e0 + bf2f(a1.x) * e1) * inv));
        o.y = f2bf(silu_((bf2f(a0.y) * e0 + bf2f(a1.y) * e1) * inv));
        o.z = f2bf(silu_((bf2f(a0.z) * e0 + bf2f(a1.z) * e1) * inv));
        o.w = f2bf(silu_((bf2f(a0.w) * e0 + bf2f(a1.w) * e1) * inv));
        *(short4*)(yall + ((size_t)b * N_ + nt * 64 + q) * 256 + p) = o;
    }
}

// ------- x2 transpose: x[b][64..256][n] -> silu -> bf16 yall[b][n][64..256] -------
__global__ __launch_bounds__(256) void k_x2t(const float* __restrict__ x,
                                             short* __restrict__ yall) {
    __shared__ short lt[64 * 66];
    const int t  = threadIdx.x;
    const int n0 = blockIdx.x << 6;
    const int c0 = 64 + (blockIdx.y << 6);
    const int b  = blockIdx.z;
    #pragma unroll
    for (int i = 0; i < 16; ++i) {
        int idx = t + i * 256;
        int cr = idx >> 6, nn = idx & 63;
        float v = x[((size_t)(b * C_ + c0 + cr)) * N_ + n0 + nn];
        lt[cr * 66 + nn] = f2bf(silu_(v));
    }
    __syncthreads();
    #pragma unroll
    for (int i = 0; i < 16; ++i) {
        int idx = t + i * 256;
        int nn = idx >> 6, cc = idx & 63;
        yall[((size_t)b * N_ + n0 + nn) * 256 + c0 + cc] = lt[cc * 66 + nn];
    }
}

// ---------------- proj: bf16 MFMA GEMM, fragments direct from global ----------------
__global__ __launch_bounds__(256) void k_proj(const short* __restrict__ yall,
        const short* __restrict__ wbf, const float* __restrict__ beta,
        float* __restrict__ out) {
    const int t = threadIdx.x;
    const int w = t >> 6, lane = t & 63;
    const int col = lane & 15, g = lane >> 4;
    const int b = blockIdx.z;
    const int o_base = (blockIdx.y << 6) + (w >> 1) * 32;
    const int n_base = (blockIdx.x << 6) + (w & 1) * 32;
    const short* pa = wbf + (o_base + col) * C_ + g * 8;
    const short* pb = yall + ((size_t)b * N_ + n_base + col) * C_ + g * 8;
    f32x4 acc00 = 0.f, acc01 = 0.f, acc10 = 0.f, acc11 = 0.f;
    #pragma unroll
    for (int kk = 0; kk < 8; ++kk) {
        short8v a0 = *(const short8v*)(pa + kk * 32);
        short8v a1 = *(const short8v*)(pa + 16 * C_ + kk * 32);
        short8v b0 = *(const short8v*)(pb + kk * 32);
        short8v b1 = *(const short8v*)(pb + 16 * C_ + kk * 32);
        acc00 = __builtin_amdgcn_mfma_f32_16x16x32_bf16(a0, b0, acc00, 0, 0, 0);
        acc01 = __builtin_amdgcn_mfma_f32_16x16x32_bf16(a0, b1, acc01, 0, 0, 0);
        acc10 = __builtin_amdgcn_mfma_f32_16x16x32_bf16(a1, b0, acc10, 0, 0, 0);
        acc11 = __builtin_amdgcn_mfma_f32_16x16x32_bf16(a1, b1, acc11, 0, 0, 0);
    }
    #pragma unroll
    for (int i = 0; i < 2; ++i) {
        const int o0 = o_base + i * 16 + g * 4;
        const f32x4 aj0 = i ? acc10 : acc00;
        const f32x4 aj1 = i ? acc11 : acc01;
        #pragma unroll
        for (int r = 0; r < 4; ++r) {
            const float be = beta[o0 + r];
            float* po = out + ((size_t)(b * C_ + o0 + r)) * N_ + n_base + col;
            po[0]  = aj0[r] + be;
            po[16] = aj1[r] + be;
        }
    }
}

extern "C" void kernel_launch(void* const* d_in, const int* in_sizes, int n_in,
                              void* d_out, int out_size, void* d_ws, size_t ws_size,
                              hipStream_t stream) {
    const float* x   = (const float*)d_in[0];
    const float* gnw = (const float*)d_in[1];
    const float* gnb = (const float*)d_in[2];
    const float* qw  = (const float*)d_in[3];
    const float* qbw = (const float*)d_in[4];
    const float* qbb = (const float*)d_in[5];
    const float* qrm = (const float*)d_in[6];
    const float* qrv = (const float*)d_in[7];
    const float* pw  = (const float*)d_in[8];
    const float* pbw = (const float*)d_in[9];
    const float* pbb = (const float*)d_in[10];
    const float* prm = (const float*)d_in[11];
    const float* prv = (const float*)d_in[12];
    float* out = (float*)d_out;
    char* wsb = (char*)d_ws;

    float* part  = (float*)wsb;                                   // 2 KB
    float* stats = (float*)(wsb + 2048);                          // 32 B
    short* qkvb  = (short*)(wsb + 4096);                          // 3 MB
    short* yall  = (short*)(wsb + 4096 + 3145728);                // [4][4096][256] bf16, 8 MB
    short* wbf   = (short*)(wsb + 4096 + 3145728 + 8388608);      // 128 KB
    float* beta  = (float*)(wsb + 4096 + 3145728 + 8388608 + 131072);  // 1 KB
    short* apart = (short*)(wsb + 4096 + 3145728 + 8388608 + 131072 + 1024);  // 512*8704B = 4.25 MB

    k_gn_part<<<256, 256, 0, stream>>>(x, part);
    k_gn_fin<<<4, 64, 0, stream>>>(part, stats);
    k_wcvt<<<256, 256, 0, stream>>>(pw, pbw, pbb, prm, prv, wbf, beta);
    k_qkv<<<256, 256, 0, stream>>>(x, gnw, gnb, qw, qbw, qbb, qrm, qrv, stats, qkvb);
    k_attn<<<512, 512, 0, stream>>>(qkvb, apart);
    k_amerge<<<256, 256, 0, stream>>>(apart, yall);
    k_x2t<<<dim3(64, 3, 4), 256, 0, stream>>>(x, yall);
    k_proj<<<dim3(64, 4, 4), 256, 0, stream>>>(yall, wbf, beta, out);
}

// Round 6
// 94.527 us; speedup vs baseline: 6.9925x; 1.1442x over previous
//
#include <hip/hip_runtime.h>
#include <hip/hip_bf16.h>
#include <math.h>

static constexpr int B_ = 4;
static constexpr int C_ = 256;
static constexpr int PD_ = 64;
static constexpr int N_ = 4096;
static constexpr int O96_ = 96;
static constexpr float EPS_ = 1e-5f;
static constexpr float SCALE_ = 0.25f;   // 16^-0.5
static constexpr float LOG2E_ = 1.4426950408889634f;

typedef __attribute__((ext_vector_type(8))) short short8v;
typedef __attribute__((ext_vector_type(4))) float f32x4;

__device__ inline short f2bf(float x) {
    __hip_bfloat16 h = __float2bfloat16(x);   // hw RNE cvt (1 VALU op)
    short r; __builtin_memcpy(&r, &h, 2); return r;
}
__device__ inline float bf2f(short s) {
    union { float f; unsigned u; } v; v.u = ((unsigned)(unsigned short)s) << 16;
    return v.f;
}
__device__ inline float silu_(float v) { return v / (1.0f + __expf(-v)); }
__device__ inline float exp2_fast(float x) {
#if __has_builtin(__builtin_amdgcn_exp2f)
    return __builtin_amdgcn_exp2f(x);
#else
    return __expf(x * 0.6931471805599453f);
#endif
}

// ---------------- GroupNorm: per-(b,c) partial sums ----------------
__global__ __launch_bounds__(256) void k_gn_part(const float* __restrict__ x,
                                                 float* __restrict__ part) {
    const int blk = blockIdx.x;            // b*64 + c
    const int b = blk >> 6, c = blk & 63;
    const float* p = x + (size_t)(b * C_ + c) * N_;
    float s = 0.f, q = 0.f;
    for (int i = threadIdx.x; i < N_; i += 256) {
        float v = p[i]; s += v; q += v * v;
    }
    for (int d = 1; d < 64; d <<= 1) {
        s += __shfl_xor(s, d, 64);
        q += __shfl_xor(q, d, 64);
    }
    __shared__ float ls[4], lq[4];
    const int lane = threadIdx.x & 63, wid = threadIdx.x >> 6;
    if (lane == 0) { ls[wid] = s; lq[wid] = q; }
    __syncthreads();
    if (threadIdx.x == 0) {
        part[2 * blk]     = ls[0] + ls[1] + ls[2] + ls[3];
        part[2 * blk + 1] = lq[0] + lq[1] + lq[2] + lq[3];
    }
}

// ---------------- GroupNorm: finalize mean/rstd per batch ----------------
__global__ __launch_bounds__(64) void k_gn_fin(const float* __restrict__ part,
                                               float* __restrict__ stats) {
    const int b = blockIdx.x;
    float s = part[2 * (b * 64 + threadIdx.x)];
    float q = part[2 * (b * 64 + threadIdx.x) + 1];
    for (int d = 1; d < 64; d <<= 1) {
        s += __shfl_xor(s, d, 64);
        q += __shfl_xor(q, d, 64);
    }
    if (threadIdx.x == 0) {
        const float inv_n = 1.0f / (float)(PD_ * N_);
        float mu = s * inv_n;
        float var = q * inv_n - mu * mu;
        stats[2 * b]     = mu;
        stats[2 * b + 1] = rsqrtf(var + EPS_);
    }
}

// ------- proj weight -> bf16 with BN scale folded; beta kept fp32 -------
__global__ __launch_bounds__(256) void k_wcvt(const float* __restrict__ pw,
        const float* __restrict__ bnw, const float* __restrict__ bnb,
        const float* __restrict__ rm,  const float* __restrict__ rv,
        short* __restrict__ wbf, float* __restrict__ beta) {
    const int idx = blockIdx.x * 256 + threadIdx.x;   // 0..65535
    const int o = idx >> 8, c = idx & 255;
    const float inv = bnw[o] * rsqrtf(rv[o] + EPS_);
    wbf[idx] = f2bf(pw[idx] * inv);
    if (c == 0) beta[o] = bnb[o] - rm[o] * inv;
}

// ------- fused GN-apply + QKV 1x1 conv + BN -> bf16 ------
// q rows (o<16) get SCALE*log2e folded so attention scores are log2-domain.
__global__ __launch_bounds__(512) void k_qkv(const float* __restrict__ x,
        const float* __restrict__ gnw, const float* __restrict__ gnb,
        const float* __restrict__ qw,  const float* __restrict__ bnw,
        const float* __restrict__ bnb, const float* __restrict__ rm,
        const float* __restrict__ rv,  const float* __restrict__ stats,
        short* __restrict__ qkvb) {
    __shared__ float wl[O96_ * PD_];
    __shared__ float binv[O96_], bbeta[O96_];
    const int t = threadIdx.x;
    const int b = blockIdx.x >> 6;
    const int n0 = (blockIdx.x & 63) << 6;
    for (int i = t; i < O96_ * PD_; i += 512) wl[i] = qw[i];
    for (int o = t; o < O96_; o += 512) {
        float inv  = bnw[o] * rsqrtf(rv[o] + EPS_);
        float beta = bnb[o] - rm[o] * inv;
        if (o < 16) { inv *= SCALE_ * LOG2E_; beta *= SCALE_ * LOG2E_; }
        binv[o] = inv; bbeta[o] = beta;
    }
    const float mu = stats[2 * b], rs = stats[2 * b + 1];
    __syncthreads();
    const int n  = n0 + (t & 63);
    const int og = t >> 6;                  // 0..7, splits the 96 outputs
    float xn[PD_];
    const float* xb = x + (size_t)b * C_ * N_ + n;
    #pragma unroll
    for (int c = 0; c < PD_; ++c)
        xn[c] = (xb[(size_t)c * N_] - mu) * rs * gnw[c] + gnb[c];
    short* qb = qkvb + (size_t)b * O96_ * N_ + n;
    for (int o = og * 12; o < og * 12 + 12; ++o) {
        const float4* wr = (const float4*)&wl[o * PD_];
        float a = 0.f;
        #pragma unroll
        for (int c4 = 0; c4 < 16; ++c4) {
            float4 w4 = wr[c4];
            a += w4.x * xn[4*c4] + w4.y * xn[4*c4+1] + w4.z * xn[4*c4+2] + w4.w * xn[4*c4+3];
        }
        qb[(size_t)o * N_] = f2bf(a * binv[o] + bbeta[o]);
    }
}

// ---------------- MFMA flash attention, fixed-max (linear state) ----------------
// grid 1024 = (b, mq, ntile) XCD-swizzled; 4 waves, each one 16-q sub-tile.
// Block covers keys [mq*1024, mq*1024+1024); scores arrive log2-domain.
__global__ __launch_bounds__(256) void k_attn(const short* __restrict__ qkvb,
                                              short* __restrict__ apart) {
    __shared__ __align__(16) char smem[24576];
    short* Qt     = (short*)smem;             // [64][24]
    short* Kt     = (short*)(smem + 3072);    // [64][24]
    short* Vs     = (short*)(smem + 6144);    // [64][72]
    short* PlBase = (short*)(smem + 15360);   // [4][16][72]

    // XCD swizzle: each XCD's 128 blocks = one batch's half of the key range.
    const int wg  = blockIdx.x;
    const int swz = (wg & 7) * 128 + (wg >> 3);
    const int b   = swz >> 8;
    const int mq  = (swz >> 6) & 3;
    const int n0  = (swz & 63) << 6;

    const int t    = threadIdx.x;
    const int w    = t >> 6;      // = q sub-tile
    const int lane = t & 63;
    const int g    = lane >> 4;   // 0..3
    const int col  = lane & 15;

    const short* qb = qkvb + (size_t)b * O96_ * N_;
    short* Pl = PlBase + w * 1152;

    // stage Q^T [q][c] once (bf16, SCALE*log2e pre-folded)
    #pragma unroll
    for (int i = 0; i < 4; ++i) {
        int idx = t + i * 256;
        int c = idx >> 6, q = idx & 63;
        Qt[q * 24 + c] = qb[(size_t)c * N_ + n0 + q];
    }

    f32x4 acc[4];
    #pragma unroll
    for (int pt = 0; pt < 4; ++pt) acc[pt] = 0.f;
    float Sr[4] = {0.f, 0.f, 0.f, 0.f};
    short8v a_q = 0;

    for (int it = 0; it < 16; ++it) {
        const int m0 = mq * 1024 + it * 64;
        __syncthreads();
        // stage K chunk 16c x 64m -> Kt[m][c], b32 writes (c-pairs)
        #pragma unroll
        for (int i = 0; i < 2; ++i) {
            int idx = t + i * 256;
            int mlow = idx & 15, cp = (idx >> 4) & 7, mh2 = idx >> 7;
            int m = mh2 * 16 + mlow, c0 = cp * 2;
            unsigned short v0 = (unsigned short)qb[(size_t)(16 + c0) * N_ + m0 + m];
            unsigned short v1 = (unsigned short)qb[(size_t)(17 + c0) * N_ + m0 + m];
            *(unsigned*)(Kt + m * 24 + c0) = (unsigned)v0 | ((unsigned)v1 << 16);
        }
        // stage V chunk 64p x 64m -> Vs[p][m], short4
        #pragma unroll
        for (int i = 0; i < 4; ++i) {
            int idx = t + i * 256;
            int p = idx >> 4, m4 = idx & 15;
            short4 v4 = *(const short4*)(qb + (size_t)(32 + p) * N_ + m0 + m4 * 4);
            *(short4*)(Vs + p * 72 + m4 * 4) = v4;
        }
        __syncthreads();
        if (it == 0) {
            if (g < 2) a_q = *(const short8v*)(Qt + (w * 16 + col) * 24 + 8 * g);
        }
        // ---- QK^T: S[16q x 64m], K-dim c=16 zero-padded to 32 ----
        f32x4 s[4];
        #pragma unroll
        for (int mt = 0; mt < 4; ++mt) {
            short8v kb = 0;
            if (g < 2) kb = *(const short8v*)(Kt + (mt * 16 + col) * 24 + 8 * g);
            f32x4 z = 0.f;
            s[mt] = __builtin_amdgcn_mfma_f32_16x16x32_bf16(a_q, kb, z, 0, 0, 0);
        }
        // ---- fixed-max softmax: p = 2^s (scores are log2-domain, tiny) ----
        #pragma unroll
        for (int r = 0; r < 4; ++r) {
            float p0 = exp2_fast(s[0][r]), p1 = exp2_fast(s[1][r]);
            float p2 = exp2_fast(s[2][r]), p3 = exp2_fast(s[3][r]);
            s[0][r] = p0; s[1][r] = p1; s[2][r] = p2; s[3][r] = p3;
            float ps = p0 + p1 + p2 + p3;
            ps += __shfl_xor(ps, 1, 64);
            ps += __shfl_xor(ps, 2, 64);
            ps += __shfl_xor(ps, 4, 64);
            ps += __shfl_xor(ps, 8, 64);
            Sr[r] += ps;
        }
        // ---- P -> bf16 -> wave-private LDS [16q][64m] pitch 72 ----
        #pragma unroll
        for (int mt = 0; mt < 4; ++mt)
            #pragma unroll
            for (int r = 0; r < 4; ++r)
                Pl[(g * 4 + r) * 72 + mt * 16 + col] = f2bf(s[mt][r]);
        // Cross-lane LDS handoff within the wave (guide rule #18).
        asm volatile("s_waitcnt lgkmcnt(0)" ::: "memory");
        __builtin_amdgcn_sched_barrier(0);
        // ---- PV: O^T[16q x 64p] += P[16x64] * V^T[64x64p] ----
        #pragma unroll
        for (int ks = 0; ks < 2; ++ks) {
            short8v pa = *(const short8v*)(Pl + col * 72 + ks * 32 + 8 * g);
            #pragma unroll
            for (int pt = 0; pt < 4; ++pt) {
                short8v vb = *(const short8v*)(Vs + (pt * 16 + col) * 72 + ks * 32 + 8 * g);
                acc[pt] = __builtin_amdgcn_mfma_f32_16x16x32_bf16(pa, vb, acc[pt], 0, 0, 0);
            }
        }
    }
    // ---- emit partial: unnormalized bf16 O [64q][64p] + S[64] f32 ----
    short* po = apart + (size_t)((b * 4 + mq) * 64 + (n0 >> 6)) * 4352;
    #pragma unroll
    for (int pt = 0; pt < 4; ++pt) {
        #pragma unroll
        for (int r = 0; r < 4; ++r)
            po[(w * 16 + g * 4 + r) * 64 + pt * 16 + col] = f2bf(acc[pt][r]);
    }
    if (col == 0) {
        float* ms = (float*)(po + 4096);
        #pragma unroll
        for (int r = 0; r < 4; ++r)
            ms[w * 16 + g * 4 + r] = Sr[r];
    }
}

// ------- merge 4 m-quarter partials -> 1/S -> silu -> bf16 yall[...,0..64) -------
__global__ __launch_bounds__(256) void k_amerge(const short* __restrict__ apart,
                                                short* __restrict__ yall) {
    const int blk = blockIdx.x;            // b*64 + nt
    const int b = blk >> 6, nt = blk & 63;
    const int t = threadIdx.x;
    const int q = t >> 2, pg = t & 3;
    const short* pk[4];
    float Ssum = 0.f;
    #pragma unroll
    for (int k = 0; k < 4; ++k) {
        pk[k] = apart + (size_t)((b * 4 + k) * 64 + nt) * 4352;
        Ssum += ((const float*)(pk[k] + 4096))[q];
    }
    const float inv = 1.0f / Ssum;
    #pragma unroll
    for (int i = 0; i < 4; ++i) {
        const int p = pg * 16 + i * 4;
        float o0 = 0.f, o1 = 0.f, o2 = 0.f, o3 = 0.f;
        #pragma unroll
        for (int k = 0; k < 4; ++k) {
            short4 a = *(const short4*)(pk[k] + q * 64 + p);
            o0 += bf2f(a.x); o1 += bf2f(a.y); o2 += bf2f(a.z); o3 += bf2f(a.w);
        }
        short4 o;
        o.x = f2bf(silu_(o0 * inv));
        o.y = f2bf(silu_(o1 * inv));
        o.z = f2bf(silu_(o2 * inv));
        o.w = f2bf(silu_(o3 * inv));
        *(short4*)(yall + ((size_t)b * N_ + nt * 64 + q) * 256 + p) = o;
    }
}

// ------- x2 transpose: x[b][64..256][n] -> silu -> bf16 yall[b][n][64..256] -------
__global__ __launch_bounds__(256) void k_x2t(const float* __restrict__ x,
                                             short* __restrict__ yall) {
    __shared__ short lt[64 * 66];
    const int t  = threadIdx.x;
    const int n0 = blockIdx.x << 6;
    const int c0 = 64 + (blockIdx.y << 6);
    const int b  = blockIdx.z;
    #pragma unroll
    for (int i = 0; i < 16; ++i) {
        int idx = t + i * 256;
        int cr = idx >> 6, nn = idx & 63;
        float v = x[((size_t)(b * C_ + c0 + cr)) * N_ + n0 + nn];
        lt[cr * 66 + nn] = f2bf(silu_(v));
    }
    __syncthreads();
    #pragma unroll
    for (int i = 0; i < 16; ++i) {
        int idx = t + i * 256;
        int nn = idx >> 6, cc = idx & 63;
        yall[((size_t)b * N_ + n0 + nn) * 256 + c0 + cc] = lt[cc * 66 + nn];
    }
}

// ---------------- proj: bf16 MFMA GEMM, fragments direct from global ----------------
__global__ __launch_bounds__(256) void k_proj(const short* __restrict__ yall,
        const short* __restrict__ wbf, const float* __restrict__ beta,
        float* __restrict__ out) {
    const int t = threadIdx.x;
    const int w = t >> 6, lane = t & 63;
    const int col = lane & 15, g = lane >> 4;
    const int b = blockIdx.z;
    const int o_base = (blockIdx.y << 6) + (w >> 1) * 32;
    const int n_base = (blockIdx.x << 6) + (w & 1) * 32;
    const short* pa = wbf + (o_base + col) * C_ + g * 8;
    const short* pb = yall + ((size_t)b * N_ + n_base + col) * C_ + g * 8;
    f32x4 acc00 = 0.f, acc01 = 0.f, acc10 = 0.f, acc11 = 0.f;
    #pragma unroll
    for (int kk = 0; kk < 8; ++kk) {
        short8v a0 = *(const short8v*)(pa + kk * 32);
        short8v a1 = *(const short8v*)(pa + 16 * C_ + kk * 32);
        short8v b0 = *(const short8v*)(pb + kk * 32);
        short8v b1 = *(const short8v*)(pb + 16 * C_ + kk * 32);
        acc00 = __builtin_amdgcn_mfma_f32_16x16x32_bf16(a0, b0, acc00, 0, 0, 0);
        acc01 = __builtin_amdgcn_mfma_f32_16x16x32_bf16(a0, b1, acc01, 0, 0, 0);
        acc10 = __builtin_amdgcn_mfma_f32_16x16x32_bf16(a1, b0, acc10, 0, 0, 0);
        acc11 = __builtin_amdgcn_mfma_f32_16x16x32_bf16(a1, b1, acc11, 0, 0, 0);
    }
    #pragma unroll
    for (int i = 0; i < 2; ++i) {
        const int o0 = o_base + i * 16 + g * 4;
        const f32x4 aj0 = i ? acc10 : acc00;
        const f32x4 aj1 = i ? acc11 : acc01;
        #pragma unroll
        for (int r = 0; r < 4; ++r) {
            const float be = beta[o0 + r];
            float* po = out + ((size_t)(b * C_ + o0 + r)) * N_ + n_base + col;
            po[0]  = aj0[r] + be;
            po[16] = aj1[r] + be;
        }
    }
}

extern "C" void kernel_launch(void* const* d_in, const int* in_sizes, int n_in,
                              void* d_out, int out_size, void* d_ws, size_t ws_size,
                              hipStream_t stream) {
    const float* x   = (const float*)d_in[0];
    const float* gnw = (const float*)d_in[1];
    const float* gnb = (const float*)d_in[2];
    const float* qw  = (const float*)d_in[3];
    const float* qbw = (const float*)d_in[4];
    const float* qbb = (const float*)d_in[5];
    const float* qrm = (const float*)d_in[6];
    const float* qrv = (const float*)d_in[7];
    const float* pw  = (const float*)d_in[8];
    const float* pbw = (const float*)d_in[9];
    const float* pbb = (const float*)d_in[10];
    const float* prm = (const float*)d_in[11];
    const float* prv = (const float*)d_in[12];
    float* out = (float*)d_out;
    char* wsb = (char*)d_ws;

    float* part  = (float*)wsb;                                   // 2 KB
    float* stats = (float*)(wsb + 2048);                          // 32 B
    short* qkvb  = (short*)(wsb + 4096);                          // 3 MB
    short* yall  = (short*)(wsb + 4096 + 3145728);                // [4][4096][256] bf16, 8 MB
    short* wbf   = (short*)(wsb + 4096 + 3145728 + 8388608);      // 128 KB
    float* beta  = (float*)(wsb + 4096 + 3145728 + 8388608 + 131072);  // 1 KB
    short* apart = (short*)(wsb + 4096 + 3145728 + 8388608 + 131072 + 1024);  // 1024*8704B = 8.9 MB

    k_gn_part<<<256, 256, 0, stream>>>(x, part);
    k_gn_fin<<<4, 64, 0, stream>>>(part, stats);
    k_wcvt<<<256, 256, 0, stream>>>(pw, pbw, pbb, prm, prv, wbf, beta);
    k_qkv<<<256, 512, 0, stream>>>(x, gnw, gnb, qw, qbw, qbb, qrm, qrv, stats, qkvb);
    k_attn<<<1024, 256, 0, stream>>>(qkvb, apart);
    k_amerge<<<256, 256, 0, stream>>>(apart, yall);
    k_x2t<<<dim3(64, 3, 4), 256, 0, stream>>>(x, yall);
    k_proj<<<dim3(64, 4, 4), 256, 0, stream>>>(yall, wbf, beta, out);
}